// Round 6
// baseline (362.940 us; speedup 1.0000x reference)
//
#include <hip/hip_runtime.h>

#define BATCH   16
#define NCGS    256
#define NATOMS  1024
#define KNN     32
#define KF      128
#define NSLICE  8

typedef __attribute__((ext_vector_type(8))) short bf16x8;
typedef __attribute__((ext_vector_type(4))) float f32x4;

#define NFRAG (13*8*4)              // step*ft*kc fragments
// Wswz layout: [fi][plane][lane] 16B each; fi = (s*8+ft)*4+kc

union U16B { bf16x8 v; uint u[4]; };

// ---------------------------------------------------------------------------
// Weight pre-swizzle: A-operand fragments, bf16 hi/lo.
// Step 0 k-labeling: identity (k = 32kc+8g+j)  [RBF generated in this order].
// Steps >=1: k-slot (kc,g,j) expects feature 16*(kc+4*(j>>2)) + 4g + (j&3),
// i.e. exactly the C-layout registers of the previous step (acc[kc],acc[kc+4]).
// ---------------------------------------------------------------------------
__global__ __launch_bounds__(256)
void prep_kernel(const float* __restrict__ mlp_W1, const float* __restrict__ mlp_W2,
                 const float* __restrict__ upd_W1, const float* __restrict__ upd_W2,
                 const float* __restrict__ dec_W1, uint* __restrict__ Wswz)
{
    int t = blockIdx.x * 256 + threadIdx.x;
    if (t >= 13*8*4*64) return;
    int lane = t & 63;
    int kc   = (t >> 6) & 3;
    int ft   = (t >> 8) & 7;
    int s    = t >> 11;

    const float* W;
    if (s < 12) {
        int d = s >> 2, ph = s & 3;
        if      (ph == 0) W = mlp_W1 + d*KF*KF;
        else if (ph == 1) W = mlp_W2 + d*KF*KF;
        else if (ph == 2) W = upd_W1 + d*KF*KF;
        else              W = upd_W2 + d*KF*KF;
    } else W = dec_W1;

    int f = ft*16 + (lane & 15);
    int g = lane >> 4;

    uint hi[4], lo[4];
    #pragma unroll
    for (int w = 0; w < 4; ++w) {
        int k0;
        if (s == 0) k0 = kc*32 + g*8 + 2*w;                      // identity (RBF)
        else        k0 = kc*16 + (w>>1)*64 + g*4 + 2*(w&1);      // C-chained
        float v0 = W[(size_t)k0*KF + f];
        float v1 = W[(size_t)(k0+1)*KF + f];
        uint b0 = __float_as_uint(v0), b1 = __float_as_uint(v1);
        hi[w] = (b0 >> 16) | (b1 & 0xffff0000u);
        float l0 = v0 - __uint_as_float(b0 & 0xffff0000u);
        float l1 = v1 - __uint_as_float(b1 & 0xffff0000u);
        lo[w] = (__float_as_uint(l0) >> 16) | (__float_as_uint(l1) & 0xffff0000u);
    }
    int fi = (s*8 + ft)*4 + kc;
    uint* ph_ = Wswz + (size_t)((fi*2 + 0)*64 + lane)*4;
    uint* pl_ = Wswz + (size_t)((fi*2 + 1)*64 + lane)*4;
    #pragma unroll
    for (int w = 0; w < 4; ++w) { ph_[w] = hi[w]; pl_[w] = lo[w]; }
}

// ---------------------------------------------------------------------------
// Fused MFMA edge-MLP, fully register-resident. 0 LDS, 0 barriers.
// grid = BATCH*64, 256 threads (4 waves); wave = 1 cg (32 edges: 2 rt tiles).
// ---------------------------------------------------------------------------
__global__ __launch_bounds__(256, 2)
void mlp_kernel(const float* __restrict__ cg_xyz, const bf16x8* __restrict__ Wf,
                const float* __restrict__ mlp_b1, const float* __restrict__ mlp_b2,
                const float* __restrict__ upd_b1, const float* __restrict__ upd_b2,
                const float* __restrict__ dec_b1, float* __restrict__ Gp)
{
    const int tid = threadIdx.x;
    const int wv  = tid >> 6;
    const int l   = tid & 63;
    const int g   = l >> 4;
    const int e0  = l & 15;
    const int b   = blockIdx.x >> 6;
    const int cg  = (blockIdx.x & 63) * 4 + wv;

    // ---- per-lane dist_vec for both owned edges (e0, e0+16) ----
    const float* cgb = cg_xyz + (size_t)b * NCGS * 3;
    const float cx = cgb[cg*3+0], cy = cgb[cg*3+1], cz = cgb[cg*3+2];
    const float d0x = cgb[(1+e0)*3+0]-cx,  d0y = cgb[(1+e0)*3+1]-cy,  d0z = cgb[(1+e0)*3+2]-cz;
    const float d1x = cgb[(17+e0)*3+0]-cx, d1y = cgb[(17+e0)*3+1]-cy, d1z = cgb[(17+e0)*3+2]-cz;
    const float dist0 = sqrtf(d0x*d0x + d0y*d0y + d0z*d0z);
    const float dist1 = sqrtf(d1x*d1x + d1y*d1y + d1z*d1z);

    // ---- RBF features directly into B-fragments (identity k-labeling) ----
    const float STEP  = 10.0f / 127.0f;
    const float COEFF = -0.5f / (STEP * STEP);
    bf16x8 bh[2][4], bl[2][4];
    #pragma unroll
    for (int rt = 0; rt < 2; ++rt) {
        float dd = rt ? dist1 : dist0;
        #pragma unroll
        for (int kc = 0; kc < 4; ++kc) {
            U16B H, L;
            #pragma unroll
            for (int w = 0; w < 4; ++w) {
                int k0 = kc*32 + g*8 + 2*w;
                float t0 = dd - (float)k0 * STEP;
                float t1 = dd - (float)(k0+1) * STEP;
                float e0f = expf(COEFF * t0 * t0);
                float e1f = expf(COEFF * t1 * t1);
                uint b0 = __float_as_uint(e0f), b1 = __float_as_uint(e1f);
                H.u[w] = (b0 >> 16) | (b1 & 0xffff0000u);
                float l0 = e0f - __uint_as_float(b0 & 0xffff0000u);
                float l1 = e1f - __uint_as_float(b1 & 0xffff0000u);
                L.u[w] = (__float_as_uint(l0) >> 16) | (__float_as_uint(l1) & 0xffff0000u);
            }
            bh[rt][kc] = H.v; bl[rt][kc] = L.v;
        }
    }

    // ---- 13 MFMA steps, all register-resident ----
    f32x4 acc[8][2];
    for (int s = 0; s < 13; ++s) {
        const float* bias; int md;
        if (s < 12) {
            int d = s >> 2, ph = s & 3;
            if      (ph == 0) { bias = mlp_b1 + d*KF; md = 0; }
            else if (ph == 1) { bias = mlp_b2 + d*KF; md = 1; }
            else if (ph == 2) { bias = upd_b1 + d*KF; md = 0; }
            else              { bias = upd_b2 + d*KF; md = 2; }
        } else { bias = dec_b1; md = 0; }

        #pragma unroll
        for (int ft = 0; ft < 8; ++ft)
            #pragma unroll
            for (int rt = 0; rt < 2; ++rt)
                acc[ft][rt] = (f32x4){0.f, 0.f, 0.f, 0.f};

        #pragma unroll
        for (int kc = 0; kc < 4; ++kc) {
            #pragma unroll
            for (int ft = 0; ft < 8; ++ft) {
                int fi = (s*8 + ft)*4 + kc;
                bf16x8 whi = Wf[(fi*2 + 0)*64 + l];
                bf16x8 wlo = Wf[(fi*2 + 1)*64 + l];
                #pragma unroll
                for (int rt = 0; rt < 2; ++rt) {
                    acc[ft][rt] = __builtin_amdgcn_mfma_f32_16x16x32_bf16(whi, bh[rt][kc], acc[ft][rt], 0, 0, 0);
                    acc[ft][rt] = __builtin_amdgcn_mfma_f32_16x16x32_bf16(whi, bl[rt][kc], acc[ft][rt], 0, 0, 0);
                    acc[ft][rt] = __builtin_amdgcn_mfma_f32_16x16x32_bf16(wlo, bh[rt][kc], acc[ft][rt], 0, 0, 0);
                }
            }
        }

        // epilogue: bias + (relu | mean | plain)
        #pragma unroll
        for (int ft = 0; ft < 8; ++ft) {
            float4 bv = *(const float4*)(bias + ft*16 + g*4);
            #pragma unroll
            for (int rt = 0; rt < 2; ++rt) {
                acc[ft][rt][0] += bv.x; acc[ft][rt][1] += bv.y;
                acc[ft][rt][2] += bv.z; acc[ft][rt][3] += bv.w;
            }
        }
        if (md == 0) {
            #pragma unroll
            for (int ft = 0; ft < 8; ++ft)
                #pragma unroll
                for (int rt = 0; rt < 2; ++rt)
                    #pragma unroll
                    for (int q = 0; q < 4; ++q)
                        acc[ft][rt][q] = fmaxf(acc[ft][rt][q], 0.f);
        } else if (md == 1) {
            #pragma unroll
            for (int ft = 0; ft < 8; ++ft)
                #pragma unroll
                for (int q = 0; q < 4; ++q) {
                    float sm = acc[ft][0][q] + acc[ft][1][q];
                    sm += __shfl_xor(sm, 1);
                    sm += __shfl_xor(sm, 2);
                    sm += __shfl_xor(sm, 4);
                    sm += __shfl_xor(sm, 8);
                    float mn = sm * (1.0f / 32.0f);
                    acc[ft][0][q] += mn;
                    acc[ft][1][q] += mn;
                }
        }

        // repack accumulators as next step's B-fragments (pure registers)
        if (s < 12) {
            #pragma unroll
            for (int rt = 0; rt < 2; ++rt)
                #pragma unroll
                for (int kc = 0; kc < 4; ++kc) {
                    float v0 = acc[kc  ][rt][0], v1 = acc[kc  ][rt][1];
                    float v2 = acc[kc  ][rt][2], v3 = acc[kc  ][rt][3];
                    float v4 = acc[kc+4][rt][0], v5 = acc[kc+4][rt][1];
                    float v6 = acc[kc+4][rt][2], v7 = acc[kc+4][rt][3];
                    uint u0=__float_as_uint(v0), u1=__float_as_uint(v1);
                    uint u2=__float_as_uint(v2), u3=__float_as_uint(v3);
                    uint u4=__float_as_uint(v4), u5=__float_as_uint(v5);
                    uint u6=__float_as_uint(v6), u7=__float_as_uint(v7);
                    U16B H, L;
                    H.u[0] = (u0>>16)|(u1&0xffff0000u);
                    H.u[1] = (u2>>16)|(u3&0xffff0000u);
                    H.u[2] = (u4>>16)|(u5&0xffff0000u);
                    H.u[3] = (u6>>16)|(u7&0xffff0000u);
                    float l0=v0-__uint_as_float(u0&0xffff0000u), l1=v1-__uint_as_float(u1&0xffff0000u);
                    float l2=v2-__uint_as_float(u2&0xffff0000u), l3=v3-__uint_as_float(u3&0xffff0000u);
                    float l4=v4-__uint_as_float(u4&0xffff0000u), l5=v5-__uint_as_float(u5&0xffff0000u);
                    float l6=v6-__uint_as_float(u6&0xffff0000u), l7=v7-__uint_as_float(u7&0xffff0000u);
                    L.u[0] = (__float_as_uint(l0)>>16)|(__float_as_uint(l1)&0xffff0000u);
                    L.u[1] = (__float_as_uint(l2)>>16)|(__float_as_uint(l3)&0xffff0000u);
                    L.u[2] = (__float_as_uint(l4)>>16)|(__float_as_uint(l5)&0xffff0000u);
                    L.u[3] = (__float_as_uint(l6)>>16)|(__float_as_uint(l7)&0xffff0000u);
                    bh[rt][kc] = H.v; bl[rt][kc] = L.v;
                }
        }
    }

    // ---- G partials: butterfly over the 16 edge-lanes, 8-sliced atomics ----
    const int slice = blockIdx.x & (NSLICE-1);
    float* Gb = Gp + ((size_t)slice*BATCH + b) * KF * 3;
    #pragma unroll
    for (int ft = 0; ft < 8; ++ft) {
        #pragma unroll
        for (int q = 0; q < 4; ++q) {
            float r0 = acc[ft][0][q], r1 = acc[ft][1][q];
            float px = r0*d0x + r1*d1x;
            float py = r0*d0y + r1*d1y;
            float pz = r0*d0z + r1*d1z;
            px += __shfl_xor(px, 1); py += __shfl_xor(py, 1); pz += __shfl_xor(pz, 1);
            px += __shfl_xor(px, 2); py += __shfl_xor(py, 2); pz += __shfl_xor(pz, 2);
            px += __shfl_xor(px, 4); py += __shfl_xor(py, 4); pz += __shfl_xor(pz, 4);
            px += __shfl_xor(px, 8); py += __shfl_xor(py, 8); pz += __shfl_xor(pz, 8);
            if (e0 < 3) {
                float pv = (e0 == 0) ? px : ((e0 == 1) ? py : pz);
                atomicAdd(Gb + (16*ft + 4*g + q)*3 + e0, pv);
            }
        }
    }
}

// ---------------------------------------------------------------------------
// dx_recon[b,o,n] = sum_k dec_W2[k,o]*G[b,k,n] + dec_b2[o]*S[b,n]
// G summed over NSLICE partials; S in closed form from cg_xyz.
// ---------------------------------------------------------------------------
__global__ __launch_bounds__(256)
void dx_kernel(const float* __restrict__ cg_xyz, const float* __restrict__ dec_W2,
               const float* __restrict__ dec_b2, const float* __restrict__ Gp,
               float* __restrict__ dxr)
{
    __shared__ float Gl[KF * 3];
    __shared__ float red[256 * 3];
    const int tid = threadIdx.x;
    const int b   = blockIdx.x >> 2;
    const int og  = blockIdx.x & 3;

    if (tid < 192) {
        float s0 = 0.f, s1 = 0.f;
        #pragma unroll
        for (int sl = 0; sl < NSLICE; ++sl) {
            const float* gp = Gp + ((size_t)sl*BATCH + b) * KF * 3;
            s0 += gp[tid]; s1 += gp[tid + 192];
        }
        Gl[tid] = s0; Gl[tid + 192] = s1;
    }
    const float* cgb = cg_xyz + (size_t)b * NCGS * 3;
    float w = ((tid >= 1 && tid <= 32) ? 256.f : 0.f) - 32.f;
    red[tid]       = w * cgb[tid*3+0];
    red[256 + tid] = w * cgb[tid*3+1];
    red[512 + tid] = w * cgb[tid*3+2];
    __syncthreads();
    for (int s2 = 128; s2 > 0; s2 >>= 1) {
        if (tid < s2) {
            red[tid]       += red[tid + s2];
            red[256 + tid] += red[256 + tid + s2];
            red[512 + tid] += red[512 + tid + s2];
        }
        __syncthreads();
    }
    const float S0 = red[0], S1 = red[256], S2 = red[512];

    const int o = og * 256 + tid;
    const float bq = dec_b2[o];
    float a0 = bq * S0, a1 = bq * S1, a2 = bq * S2;
    #pragma unroll 4
    for (int k = 0; k < KF; ++k) {
        float wvv = dec_W2[k * NATOMS + o];
        a0 = fmaf(wvv, Gl[k*3+0], a0);
        a1 = fmaf(wvv, Gl[k*3+1], a1);
        a2 = fmaf(wvv, Gl[k*3+2], a2);
    }
    float* dp = dxr + ((size_t)b * NATOMS + o) * 3;
    dp[0] = a0; dp[1] = a1; dp[2] = a2;
}

// ---------------------------------------------------------------------------
__global__ __launch_bounds__(256)
void cgo_kernel(const float* __restrict__ assign_norm, const float* __restrict__ dxr,
                float* __restrict__ cgo)
{
    __shared__ float dxl[64 * 3];
    const int tid = threadIdx.x;
    const int b   = blockIdx.x >> 4;
    const int a0  = (blockIdx.x & 15) * 64;
    if (tid < 192) dxl[tid] = dxr[((size_t)b * NATOMS + a0) * 3 + tid];
    __syncthreads();
    float c0 = 0.f, c1 = 0.f, c2 = 0.f;
    const float* an = assign_norm + ((size_t)b * NATOMS + a0) * NCGS + tid;
    #pragma unroll 4
    for (int a = 0; a < 64; ++a) {
        float v = an[(size_t)a * NCGS];
        c0 = fmaf(v, dxl[a*3+0], c0);
        c1 = fmaf(v, dxl[a*3+1], c1);
        c2 = fmaf(v, dxl[a*3+2], c2);
    }
    float* cp = cgo + ((size_t)b * NCGS + tid) * 3;
    atomicAdd(cp+0, c0); atomicAdd(cp+1, c1); atomicAdd(cp+2, c2);
}

// ---------------------------------------------------------------------------
__global__ __launch_bounds__(256)
void recon_kernel(const float* __restrict__ cg_xyz, const float* __restrict__ cgo,
                  const float* __restrict__ dxr, const int* __restrict__ assign_idx,
                  float* __restrict__ out)
{
    int i = blockIdx.x * 256 + threadIdx.x;
    int b   = i / (NATOMS * 3);
    int rem = i - b * (NATOMS * 3);
    int a   = rem / 3;
    int n   = rem - a * 3;
    int ia  = assign_idx[a];
    float v = cg_xyz[((size_t)b*NCGS + ia)*3 + n]
            - cgo[((size_t)b*NCGS + ia)*3 + n]
            + dxr[((size_t)b*NATOMS + a)*3 + n];
    out[i] = v;
}

// ---------------------------------------------------------------------------
extern "C" void kernel_launch(void* const* d_in, const int* in_sizes, int n_in,
                              void* d_out, int out_size, void* d_ws, size_t ws_size,
                              hipStream_t stream)
{
    const float* soft_assign = (const float*)d_in[0];
    const float* xyz         = (const float*)d_in[1];
    const float* cg_xyz      = (const float*)d_in[2];
    const float* assign_norm = (const float*)d_in[3];
    const int*   assign_idx  = (const int*)  d_in[4];
    const float* mlp_W1 = (const float*)d_in[5];
    const float* mlp_b1 = (const float*)d_in[6];
    const float* mlp_W2 = (const float*)d_in[7];
    const float* mlp_b2 = (const float*)d_in[8];
    const float* upd_W1 = (const float*)d_in[9];
    const float* upd_b1 = (const float*)d_in[10];
    const float* upd_W2 = (const float*)d_in[11];
    const float* upd_b2 = (const float*)d_in[12];
    const float* dec_W1 = (const float*)d_in[13];
    const float* dec_b1 = (const float*)d_in[14];
    const float* dec_W2 = (const float*)d_in[15];
    const float* dec_b2 = (const float*)d_in[16];

    float* out = (float*)d_out;

    // ws layout: Wswz (832 KB) | Gp (192 KB) | cgo (48 KB) | dxr (192 KB)
    uint*  Wswz = (uint*)d_ws;
    float* Gp   = (float*)d_ws + NFRAG*2*64*4;
    float* cgo  = Gp + NSLICE * BATCH * KF * 3;
    float* dxr  = cgo + BATCH * NCGS * 3;

    hipMemcpyAsync(out, soft_assign, (size_t)BATCH*NATOMS*NCGS*sizeof(float),
                   hipMemcpyDeviceToDevice, stream);
    hipMemcpyAsync(out + (size_t)BATCH*NATOMS*NCGS, xyz,
                   (size_t)BATCH*NATOMS*3*sizeof(float),
                   hipMemcpyDeviceToDevice, stream);
    hipMemsetAsync(Gp, 0,
        (size_t)(NSLICE*BATCH*KF*3 + BATCH*NCGS*3)*sizeof(float), stream);

    prep_kernel<<<104, 256, 0, stream>>>(mlp_W1, mlp_W2, upd_W1, upd_W2, dec_W1, Wswz);
    mlp_kernel<<<BATCH*64, 256, 0, stream>>>(cg_xyz, (const bf16x8*)Wswz,
        mlp_b1, mlp_b2, upd_b1, upd_b2, dec_b1, Gp);
    dx_kernel<<<BATCH*4, 256, 0, stream>>>(cg_xyz, dec_W2, dec_b2, Gp, dxr);
    cgo_kernel<<<BATCH*16, 256, 0, stream>>>(assign_norm, dxr, cgo);
    recon_kernel<<<(BATCH*NATOMS*3)/256, 256, 0, stream>>>(
        cg_xyz, cgo, dxr, assign_idx,
        out + (size_t)BATCH*NATOMS*NCGS + (size_t)BATCH*NATOMS*3);
}

// Round 7
// 357.596 us; speedup vs baseline: 1.0149x; 1.0149x over previous
//
#include <hip/hip_runtime.h>

#define BATCH   16
#define NCGS    256
#define NATOMS  1024
#define KNN     32
#define KF      128
#define NSLICE  8

typedef __attribute__((ext_vector_type(8))) short bf16x8;
typedef __attribute__((ext_vector_type(4))) float f32x4;

#define NFRAG (13*8*4)              // step*ft*kc fragments
// Wswz layout: [fi][plane][lane] 16B each; fi = (s*8+ft)*4+kc

union U16B { bf16x8 v; uint u[4]; };

// ---------------------------------------------------------------------------
// Weight pre-swizzle: A-operand fragments, bf16 hi/lo.
// Step 0 k-labeling: identity (k = 32kc+8g+j)  [RBF generated in this order].
// Steps >=1: k-slot (kc,g,j) expects feature 16*(kc+4*(j>>2)) + 4g + (j&3),
// i.e. exactly the C-layout registers of the previous step (acc[kc],acc[kc+4]).
// ---------------------------------------------------------------------------
__global__ __launch_bounds__(256)
void prep_kernel(const float* __restrict__ mlp_W1, const float* __restrict__ mlp_W2,
                 const float* __restrict__ upd_W1, const float* __restrict__ upd_W2,
                 const float* __restrict__ dec_W1, uint* __restrict__ Wswz)
{
    int t = blockIdx.x * 256 + threadIdx.x;
    if (t >= 13*8*4*64) return;
    int lane = t & 63;
    int kc   = (t >> 6) & 3;
    int ft   = (t >> 8) & 7;
    int s    = t >> 11;

    const float* W;
    if (s < 12) {
        int d = s >> 2, ph = s & 3;
        if      (ph == 0) W = mlp_W1 + d*KF*KF;
        else if (ph == 1) W = mlp_W2 + d*KF*KF;
        else if (ph == 2) W = upd_W1 + d*KF*KF;
        else              W = upd_W2 + d*KF*KF;
    } else W = dec_W1;

    int f = ft*16 + (lane & 15);
    int g = lane >> 4;

    uint hi[4], lo[4];
    #pragma unroll
    for (int w = 0; w < 4; ++w) {
        int k0;
        if (s == 0) k0 = kc*32 + g*8 + 2*w;                      // identity (RBF)
        else        k0 = kc*16 + (w>>1)*64 + g*4 + 2*(w&1);      // C-chained
        float v0 = W[(size_t)k0*KF + f];
        float v1 = W[(size_t)(k0+1)*KF + f];
        uint b0 = __float_as_uint(v0), b1 = __float_as_uint(v1);
        hi[w] = (b0 >> 16) | (b1 & 0xffff0000u);
        float l0 = v0 - __uint_as_float(b0 & 0xffff0000u);
        float l1 = v1 - __uint_as_float(b1 & 0xffff0000u);
        lo[w] = (__float_as_uint(l0) >> 16) | (__float_as_uint(l1) & 0xffff0000u);
    }
    int fi = (s*8 + ft)*4 + kc;
    uint* ph_ = Wswz + (size_t)((fi*2 + 0)*64 + lane)*4;
    uint* pl_ = Wswz + (size_t)((fi*2 + 1)*64 + lane)*4;
    #pragma unroll
    for (int w = 0; w < 4; ++w) { ph_[w] = hi[w]; pl_[w] = lo[w]; }
}

// ---------------------------------------------------------------------------
// Templated load/compute groups: all register indices compile-time constants.
// Group = (KC, FH): 4 ft-tiles (FH*4..FH*4+3), one kc, hi+lo planes = 8 frags.
// ---------------------------------------------------------------------------
template<int KC, int FH>
__device__ __forceinline__ void loadw(bf16x8 (&wb)[8], const bf16x8* __restrict__ Ws, int l)
{
    #pragma unroll
    for (int i = 0; i < 4; ++i) {
        const int idx = ((FH*4 + i)*4 + KC)*2;
        wb[i*2+0] = Ws[(idx+0)*64 + l];
        wb[i*2+1] = Ws[(idx+1)*64 + l];
    }
}

template<int KC, int FH>
__device__ __forceinline__ void compw(const bf16x8 (&wb)[8],
        const bf16x8 (&bh)[2][4], const bf16x8 (&bl)[2][4], f32x4 (&acc)[8][2])
{
    #pragma unroll
    for (int i = 0; i < 4; ++i) {
        const int ft = FH*4 + i;
        bf16x8 whi = wb[i*2+0], wlo = wb[i*2+1];
        #pragma unroll
        for (int rt = 0; rt < 2; ++rt) {
            acc[ft][rt] = __builtin_amdgcn_mfma_f32_16x16x32_bf16(whi, bh[rt][KC], acc[ft][rt], 0, 0, 0);
            acc[ft][rt] = __builtin_amdgcn_mfma_f32_16x16x32_bf16(whi, bl[rt][KC], acc[ft][rt], 0, 0, 0);
            acc[ft][rt] = __builtin_amdgcn_mfma_f32_16x16x32_bf16(wlo, bh[rt][KC], acc[ft][rt], 0, 0, 0);
        }
    }
}

// ---------------------------------------------------------------------------
// Fused MFMA edge-MLP, register-resident, explicit W double-buffer prefetch.
// grid = BATCH*64, 256 threads (4 waves); wave = 1 cg (32 edges: 2 rt tiles).
// ---------------------------------------------------------------------------
__global__ __launch_bounds__(256, 2)
void mlp_kernel(const float* __restrict__ cg_xyz, const bf16x8* __restrict__ Wf,
                const float* __restrict__ mlp_b1, const float* __restrict__ mlp_b2,
                const float* __restrict__ upd_b1, const float* __restrict__ upd_b2,
                const float* __restrict__ dec_b1, float* __restrict__ Gp)
{
    const int tid = threadIdx.x;
    const int wv  = tid >> 6;
    const int l   = tid & 63;
    const int g   = l >> 4;
    const int e0  = l & 15;
    const int b   = blockIdx.x >> 6;
    const int cg  = (blockIdx.x & 63) * 4 + wv;

    // ---- per-lane dist_vec for both owned edges (e0, e0+16) ----
    const float* cgb = cg_xyz + (size_t)b * NCGS * 3;
    const float cx = cgb[cg*3+0], cy = cgb[cg*3+1], cz = cgb[cg*3+2];
    const float d0x = cgb[(1+e0)*3+0]-cx,  d0y = cgb[(1+e0)*3+1]-cy,  d0z = cgb[(1+e0)*3+2]-cz;
    const float d1x = cgb[(17+e0)*3+0]-cx, d1y = cgb[(17+e0)*3+1]-cy, d1z = cgb[(17+e0)*3+2]-cz;
    const float dist0 = sqrtf(d0x*d0x + d0y*d0y + d0z*d0z);
    const float dist1 = sqrtf(d1x*d1x + d1y*d1y + d1z*d1z);

    // ---- RBF features directly into B-fragments (identity k-labeling) ----
    const float STEP  = 10.0f / 127.0f;
    const float COEFF = -0.5f / (STEP * STEP);
    bf16x8 bh[2][4], bl[2][4];
    #pragma unroll
    for (int rt = 0; rt < 2; ++rt) {
        float dd = rt ? dist1 : dist0;
        #pragma unroll
        for (int kc = 0; kc < 4; ++kc) {
            U16B H, L;
            #pragma unroll
            for (int w = 0; w < 4; ++w) {
                int k0 = kc*32 + g*8 + 2*w;
                float t0 = dd - (float)k0 * STEP;
                float t1 = dd - (float)(k0+1) * STEP;
                float e0f = __expf(COEFF * t0 * t0);
                float e1f = __expf(COEFF * t1 * t1);
                uint b0 = __float_as_uint(e0f), b1 = __float_as_uint(e1f);
                H.u[w] = (b0 >> 16) | (b1 & 0xffff0000u);
                float l0 = e0f - __uint_as_float(b0 & 0xffff0000u);
                float l1 = e1f - __uint_as_float(b1 & 0xffff0000u);
                L.u[w] = (__float_as_uint(l0) >> 16) | (__float_as_uint(l1) & 0xffff0000u);
            }
            bh[rt][kc] = H.v; bl[rt][kc] = L.v;
        }
    }

    // ---- 13 MFMA steps, register-resident, double-buffered W prefetch ----
    f32x4 acc[8][2];
    bf16x8 wb0[8], wb1[8];
    for (int s = 0; s < 13; ++s) {
        const float* bias; int md;
        if (s < 12) {
            int d = s >> 2, ph = s & 3;
            if      (ph == 0) { bias = mlp_b1 + d*KF; md = 0; }
            else if (ph == 1) { bias = mlp_b2 + d*KF; md = 1; }
            else if (ph == 2) { bias = upd_b1 + d*KF; md = 0; }
            else              { bias = upd_b2 + d*KF; md = 2; }
        } else { bias = dec_b1; md = 0; }

        const bf16x8* Ws = Wf + (size_t)(s*8)*4*2*64;

        // first group's loads go out before anything else
        loadw<0,0>(wb0, Ws, l);

        // acc init folds the bias (C row = feature = ft*16 + 4g + q)
        #pragma unroll
        for (int ft = 0; ft < 8; ++ft) {
            float4 bv = *(const float4*)(bias + ft*16 + g*4);
            acc[ft][0] = (f32x4){bv.x, bv.y, bv.z, bv.w};
            acc[ft][1] = acc[ft][0];
        }

        // software-pipelined 8-group schedule: load(i+1) || compute(i)
        loadw<0,1>(wb1, Ws, l);  compw<0,0>(wb0, bh, bl, acc);
        loadw<1,0>(wb0, Ws, l);  compw<0,1>(wb1, bh, bl, acc);
        loadw<1,1>(wb1, Ws, l);  compw<1,0>(wb0, bh, bl, acc);
        loadw<2,0>(wb0, Ws, l);  compw<1,1>(wb1, bh, bl, acc);
        loadw<2,1>(wb1, Ws, l);  compw<2,0>(wb0, bh, bl, acc);
        loadw<3,0>(wb0, Ws, l);  compw<2,1>(wb1, bh, bl, acc);
        loadw<3,1>(wb1, Ws, l);  compw<3,0>(wb0, bh, bl, acc);
                                 compw<3,1>(wb1, bh, bl, acc);

        // epilogue: (relu | mean | plain) — bias already folded
        if (md == 0) {
            #pragma unroll
            for (int ft = 0; ft < 8; ++ft)
                #pragma unroll
                for (int rt = 0; rt < 2; ++rt)
                    #pragma unroll
                    for (int q = 0; q < 4; ++q)
                        acc[ft][rt][q] = fmaxf(acc[ft][rt][q], 0.f);
        } else if (md == 1) {
            #pragma unroll
            for (int ft = 0; ft < 8; ++ft)
                #pragma unroll
                for (int q = 0; q < 4; ++q) {
                    float sm = acc[ft][0][q] + acc[ft][1][q];
                    sm += __shfl_xor(sm, 1);
                    sm += __shfl_xor(sm, 2);
                    sm += __shfl_xor(sm, 4);
                    sm += __shfl_xor(sm, 8);
                    float mn = sm * (1.0f / 32.0f);
                    acc[ft][0][q] += mn;
                    acc[ft][1][q] += mn;
                }
        }

        // repack accumulators as next step's B-fragments (pure registers)
        if (s < 12) {
            #pragma unroll
            for (int rt = 0; rt < 2; ++rt)
                #pragma unroll
                for (int kc = 0; kc < 4; ++kc) {
                    float v0 = acc[kc  ][rt][0], v1 = acc[kc  ][rt][1];
                    float v2 = acc[kc  ][rt][2], v3 = acc[kc  ][rt][3];
                    float v4 = acc[kc+4][rt][0], v5 = acc[kc+4][rt][1];
                    float v6 = acc[kc+4][rt][2], v7 = acc[kc+4][rt][3];
                    uint u0=__float_as_uint(v0), u1=__float_as_uint(v1);
                    uint u2=__float_as_uint(v2), u3=__float_as_uint(v3);
                    uint u4=__float_as_uint(v4), u5=__float_as_uint(v5);
                    uint u6=__float_as_uint(v6), u7=__float_as_uint(v7);
                    U16B H, L;
                    H.u[0] = (u0>>16)|(u1&0xffff0000u);
                    H.u[1] = (u2>>16)|(u3&0xffff0000u);
                    H.u[2] = (u4>>16)|(u5&0xffff0000u);
                    H.u[3] = (u6>>16)|(u7&0xffff0000u);
                    float l0=v0-__uint_as_float(u0&0xffff0000u), l1=v1-__uint_as_float(u1&0xffff0000u);
                    float l2=v2-__uint_as_float(u2&0xffff0000u), l3=v3-__uint_as_float(u3&0xffff0000u);
                    float l4=v4-__uint_as_float(u4&0xffff0000u), l5=v5-__uint_as_float(u5&0xffff0000u);
                    float l6=v6-__uint_as_float(u6&0xffff0000u), l7=v7-__uint_as_float(u7&0xffff0000u);
                    L.u[0] = (__float_as_uint(l0)>>16)|(__float_as_uint(l1)&0xffff0000u);
                    L.u[1] = (__float_as_uint(l2)>>16)|(__float_as_uint(l3)&0xffff0000u);
                    L.u[2] = (__float_as_uint(l4)>>16)|(__float_as_uint(l5)&0xffff0000u);
                    L.u[3] = (__float_as_uint(l6)>>16)|(__float_as_uint(l7)&0xffff0000u);
                    bh[rt][kc] = H.v; bl[rt][kc] = L.v;
                }
        }
    }

    // ---- G partials: butterfly over the 16 edge-lanes, 8-sliced atomics ----
    const int slice = blockIdx.x & (NSLICE-1);
    float* Gb = Gp + ((size_t)slice*BATCH + b) * KF * 3;
    #pragma unroll
    for (int ft = 0; ft < 8; ++ft) {
        #pragma unroll
        for (int q = 0; q < 4; ++q) {
            float r0 = acc[ft][0][q], r1 = acc[ft][1][q];
            float px = r0*d0x + r1*d1x;
            float py = r0*d0y + r1*d1y;
            float pz = r0*d0z + r1*d1z;
            px += __shfl_xor(px, 1); py += __shfl_xor(py, 1); pz += __shfl_xor(pz, 1);
            px += __shfl_xor(px, 2); py += __shfl_xor(py, 2); pz += __shfl_xor(pz, 2);
            px += __shfl_xor(px, 4); py += __shfl_xor(py, 4); pz += __shfl_xor(pz, 4);
            px += __shfl_xor(px, 8); py += __shfl_xor(py, 8); pz += __shfl_xor(pz, 8);
            if (e0 < 3) {
                float pv = (e0 == 0) ? px : ((e0 == 1) ? py : pz);
                atomicAdd(Gb + (16*ft + 4*g + q)*3 + e0, pv);
            }
        }
    }
}

// ---------------------------------------------------------------------------
// dx_recon[b,o,n] = sum_k dec_W2[k,o]*G[b,k,n] + dec_b2[o]*S[b,n]
// G summed over NSLICE partials; S in closed form from cg_xyz.
// ---------------------------------------------------------------------------
__global__ __launch_bounds__(256)
void dx_kernel(const float* __restrict__ cg_xyz, const float* __restrict__ dec_W2,
               const float* __restrict__ dec_b2, const float* __restrict__ Gp,
               float* __restrict__ dxr)
{
    __shared__ float Gl[KF * 3];
    __shared__ float red[256 * 3];
    const int tid = threadIdx.x;
    const int b   = blockIdx.x >> 2;
    const int og  = blockIdx.x & 3;

    if (tid < 192) {
        float s0 = 0.f, s1 = 0.f;
        #pragma unroll
        for (int sl = 0; sl < NSLICE; ++sl) {
            const float* gp = Gp + ((size_t)sl*BATCH + b) * KF * 3;
            s0 += gp[tid]; s1 += gp[tid + 192];
        }
        Gl[tid] = s0; Gl[tid + 192] = s1;
    }
    const float* cgb = cg_xyz + (size_t)b * NCGS * 3;
    float w = ((tid >= 1 && tid <= 32) ? 256.f : 0.f) - 32.f;
    red[tid]       = w * cgb[tid*3+0];
    red[256 + tid] = w * cgb[tid*3+1];
    red[512 + tid] = w * cgb[tid*3+2];
    __syncthreads();
    for (int s2 = 128; s2 > 0; s2 >>= 1) {
        if (tid < s2) {
            red[tid]       += red[tid + s2];
            red[256 + tid] += red[256 + tid + s2];
            red[512 + tid] += red[512 + tid + s2];
        }
        __syncthreads();
    }
    const float S0 = red[0], S1 = red[256], S2 = red[512];

    const int o = og * 256 + tid;
    const float bq = dec_b2[o];
    float a0 = bq * S0, a1 = bq * S1, a2 = bq * S2;
    #pragma unroll 4
    for (int k = 0; k < KF; ++k) {
        float wvv = dec_W2[k * NATOMS + o];
        a0 = fmaf(wvv, Gl[k*3+0], a0);
        a1 = fmaf(wvv, Gl[k*3+1], a1);
        a2 = fmaf(wvv, Gl[k*3+2], a2);
    }
    float* dp = dxr + ((size_t)b * NATOMS + o) * 3;
    dp[0] = a0; dp[1] = a1; dp[2] = a2;
}

// ---------------------------------------------------------------------------
__global__ __launch_bounds__(256)
void cgo_kernel(const float* __restrict__ assign_norm, const float* __restrict__ dxr,
                float* __restrict__ cgo)
{
    __shared__ float dxl[64 * 3];
    const int tid = threadIdx.x;
    const int b   = blockIdx.x >> 4;
    const int a0  = (blockIdx.x & 15) * 64;
    if (tid < 192) dxl[tid] = dxr[((size_t)b * NATOMS + a0) * 3 + tid];
    __syncthreads();
    float c0 = 0.f, c1 = 0.f, c2 = 0.f;
    const float* an = assign_norm + ((size_t)b * NATOMS + a0) * NCGS + tid;
    #pragma unroll 4
    for (int a = 0; a < 64; ++a) {
        float v = an[(size_t)a * NCGS];
        c0 = fmaf(v, dxl[a*3+0], c0);
        c1 = fmaf(v, dxl[a*3+1], c1);
        c2 = fmaf(v, dxl[a*3+2], c2);
    }
    float* cp = cgo + ((size_t)b * NCGS + tid) * 3;
    atomicAdd(cp+0, c0); atomicAdd(cp+1, c1); atomicAdd(cp+2, c2);
}

// ---------------------------------------------------------------------------
__global__ __launch_bounds__(256)
void recon_kernel(const float* __restrict__ cg_xyz, const float* __restrict__ cgo,
                  const float* __restrict__ dxr, const int* __restrict__ assign_idx,
                  float* __restrict__ out)
{
    int i = blockIdx.x * 256 + threadIdx.x;
    int b   = i / (NATOMS * 3);
    int rem = i - b * (NATOMS * 3);
    int a   = rem / 3;
    int n   = rem - a * 3;
    int ia  = assign_idx[a];
    float v = cg_xyz[((size_t)b*NCGS + ia)*3 + n]
            - cgo[((size_t)b*NCGS + ia)*3 + n]
            + dxr[((size_t)b*NATOMS + a)*3 + n];
    out[i] = v;
}

// ---------------------------------------------------------------------------
extern "C" void kernel_launch(void* const* d_in, const int* in_sizes, int n_in,
                              void* d_out, int out_size, void* d_ws, size_t ws_size,
                              hipStream_t stream)
{
    const float* soft_assign = (const float*)d_in[0];
    const float* xyz         = (const float*)d_in[1];
    const float* cg_xyz      = (const float*)d_in[2];
    const float* assign_norm = (const float*)d_in[3];
    const int*   assign_idx  = (const int*)  d_in[4];
    const float* mlp_W1 = (const float*)d_in[5];
    const float* mlp_b1 = (const float*)d_in[6];
    const float* mlp_W2 = (const float*)d_in[7];
    const float* mlp_b2 = (const float*)d_in[8];
    const float* upd_W1 = (const float*)d_in[9];
    const float* upd_b1 = (const float*)d_in[10];
    const float* upd_W2 = (const float*)d_in[11];
    const float* upd_b2 = (const float*)d_in[12];
    const float* dec_W1 = (const float*)d_in[13];
    const float* dec_b1 = (const float*)d_in[14];
    const float* dec_W2 = (const float*)d_in[15];
    const float* dec_b2 = (const float*)d_in[16];

    float* out = (float*)d_out;

    // ws layout: Wswz (832 KB) | Gp (192 KB) | cgo (48 KB) | dxr (192 KB)
    uint*  Wswz = (uint*)d_ws;
    float* Gp   = (float*)d_ws + NFRAG*2*64*4;
    float* cgo  = Gp + NSLICE * BATCH * KF * 3;
    float* dxr  = cgo + BATCH * NCGS * 3;

    hipMemcpyAsync(out, soft_assign, (size_t)BATCH*NATOMS*NCGS*sizeof(float),
                   hipMemcpyDeviceToDevice, stream);
    hipMemcpyAsync(out + (size_t)BATCH*NATOMS*NCGS, xyz,
                   (size_t)BATCH*NATOMS*3*sizeof(float),
                   hipMemcpyDeviceToDevice, stream);
    hipMemsetAsync(Gp, 0,
        (size_t)(NSLICE*BATCH*KF*3 + BATCH*NCGS*3)*sizeof(float), stream);

    prep_kernel<<<104, 256, 0, stream>>>(mlp_W1, mlp_W2, upd_W1, upd_W2, dec_W1, Wswz);
    mlp_kernel<<<BATCH*64, 256, 0, stream>>>(cg_xyz, (const bf16x8*)Wswz,
        mlp_b1, mlp_b2, upd_b1, upd_b2, dec_b1, Gp);
    dx_kernel<<<BATCH*4, 256, 0, stream>>>(cg_xyz, dec_W2, dec_b2, Gp, dxr);
    cgo_kernel<<<BATCH*16, 256, 0, stream>>>(assign_norm, dxr, cgo);
    recon_kernel<<<(BATCH*NATOMS*3)/256, 256, 0, stream>>>(
        cg_xyz, cgo, dxr, assign_idx,
        out + (size_t)BATCH*NATOMS*NCGS + (size_t)BATCH*NATOMS*3);
}

// Round 8
// 301.197 us; speedup vs baseline: 1.2050x; 1.1873x over previous
//
#include <hip/hip_runtime.h>

#define BATCH   16
#define NCGS    256
#define NATOMS  1024
#define KNN     32
#define KF      128
#define NSLICE  8

typedef __attribute__((ext_vector_type(8))) short bf16x8;
typedef __attribute__((ext_vector_type(4))) float f32x4;

#define NFRAG (13*8*4)              // step*ft*kc fragments
// Wswz layout: [fi][plane][lane] 16B each; fi = (s*8+ft)*4+kc

union U16B { bf16x8 v; uint u[4]; };

// ---------------------------------------------------------------------------
// Weight pre-swizzle: A-operand fragments, bf16 hi/lo.  (unchanged)
// ---------------------------------------------------------------------------
__global__ __launch_bounds__(256)
void prep_kernel(const float* __restrict__ mlp_W1, const float* __restrict__ mlp_W2,
                 const float* __restrict__ upd_W1, const float* __restrict__ upd_W2,
                 const float* __restrict__ dec_W1, uint* __restrict__ Wswz)
{
    int t = blockIdx.x * 256 + threadIdx.x;
    if (t >= 13*8*4*64) return;
    int lane = t & 63;
    int kc   = (t >> 6) & 3;
    int ft   = (t >> 8) & 7;
    int s    = t >> 11;

    const float* W;
    if (s < 12) {
        int d = s >> 2, ph = s & 3;
        if      (ph == 0) W = mlp_W1 + d*KF*KF;
        else if (ph == 1) W = mlp_W2 + d*KF*KF;
        else if (ph == 2) W = upd_W1 + d*KF*KF;
        else              W = upd_W2 + d*KF*KF;
    } else W = dec_W1;

    int f = ft*16 + (lane & 15);
    int g = lane >> 4;

    uint hi[4], lo[4];
    #pragma unroll
    for (int w = 0; w < 4; ++w) {
        int k0;
        if (s == 0) k0 = kc*32 + g*8 + 2*w;                      // identity (RBF)
        else        k0 = kc*16 + (w>>1)*64 + g*4 + 2*(w&1);      // C-chained
        float v0 = W[(size_t)k0*KF + f];
        float v1 = W[(size_t)(k0+1)*KF + f];
        uint b0 = __float_as_uint(v0), b1 = __float_as_uint(v1);
        hi[w] = (b0 >> 16) | (b1 & 0xffff0000u);
        float l0 = v0 - __uint_as_float(b0 & 0xffff0000u);
        float l1 = v1 - __uint_as_float(b1 & 0xffff0000u);
        lo[w] = (__float_as_uint(l0) >> 16) | (__float_as_uint(l1) & 0xffff0000u);
    }
    int fi = (s*8 + ft)*4 + kc;
    uint* ph_ = Wswz + (size_t)((fi*2 + 0)*64 + lane)*4;
    uint* pl_ = Wswz + (size_t)((fi*2 + 1)*64 + lane)*4;
    #pragma unroll
    for (int w = 0; w < 4; ++w) { ph_[w] = hi[w]; pl_[w] = lo[w]; }
}

// ---------------------------------------------------------------------------
// global->LDS direct staging (16B per lane; LDS dest is wave-uniform base).
// ---------------------------------------------------------------------------
__device__ __forceinline__ void gload_lds16(const void* g, void* l)
{
    __builtin_amdgcn_global_load_lds(
        (const __attribute__((address_space(1))) void*)g,
        (__attribute__((address_space(3))) void*)l, 16, 0, 0);
}

// stage one half-step (32 frags x 1KB) of step s, half hf, into buf.
// wave wv issues 8 gl_lds; frag j=(kc2*8+ft)*2+p lives at buf+j*1024.
__device__ __forceinline__ void stage_half(const char* __restrict__ Wbase,
                                           int s, int hf, char* buf, int wv, int l)
{
    #pragma unroll
    for (int q = 0; q < 8; ++q) {
        int j   = wv*8 + q;
        int kc2 = j >> 4, ft = (j >> 1) & 7, p = j & 1;
        int fi  = (s*8 + ft)*4 + (2*hf + kc2);
        const char* g = Wbase + ((size_t)(fi*2 + p))*1024 + (size_t)l*16;
        gload_lds16(g, buf + (size_t)j*1024);
    }
}

// compute one (KC, FH) group: 8 ds_read_b128 + 24 MFMA. KC compile-time (reg idx).
template<int KC, int FH>
__device__ __forceinline__ void comp_grp(const char* buf, int l,
        const bf16x8 (&bh)[2][4], const bf16x8 (&bl)[2][4], f32x4 (&acc)[8][2])
{
    constexpr int KC2 = KC & 1;
    #pragma unroll
    for (int i = 0; i < 4; ++i) {
        const int ft = FH*4 + i;
        bf16x8 whi = *(const bf16x8*)(buf + (size_t)(((KC2*8 + ft)*2 + 0)*1024) + (size_t)l*16);
        bf16x8 wlo = *(const bf16x8*)(buf + (size_t)(((KC2*8 + ft)*2 + 1)*1024) + (size_t)l*16);
        #pragma unroll
        for (int rt = 0; rt < 2; ++rt) {
            acc[ft][rt] = __builtin_amdgcn_mfma_f32_16x16x32_bf16(whi, bh[rt][KC], acc[ft][rt], 0, 0, 0);
            acc[ft][rt] = __builtin_amdgcn_mfma_f32_16x16x32_bf16(whi, bl[rt][KC], acc[ft][rt], 0, 0, 0);
            acc[ft][rt] = __builtin_amdgcn_mfma_f32_16x16x32_bf16(wlo, bh[rt][KC], acc[ft][rt], 0, 0, 0);
        }
    }
}

// ---------------------------------------------------------------------------
// Fused MFMA edge-MLP. W staged via LDS (shared by 4 waves), half-step dbuf.
// grid = BATCH*64, 256 threads (4 waves); wave = 1 cg (32 edges: 2 rt tiles).
// ---------------------------------------------------------------------------
__global__ __launch_bounds__(256, 2)
void mlp_kernel(const float* __restrict__ cg_xyz, const char* __restrict__ Wf,
                const float* __restrict__ mlp_b1, const float* __restrict__ mlp_b2,
                const float* __restrict__ upd_b1, const float* __restrict__ upd_b2,
                const float* __restrict__ dec_b1, float* __restrict__ Gp)
{
    __shared__ __align__(16) char Wlds[2][32*1024];   // 64 KB: half-step dbuf

    const int tid = threadIdx.x;
    const int wv  = tid >> 6;
    const int l   = tid & 63;
    const int g   = l >> 4;
    const int e0  = l & 15;
    const int b   = blockIdx.x >> 6;
    const int cg  = (blockIdx.x & 63) * 4 + wv;

    // ---- prologue: stage step 0 / half 0 while doing setup VALU ----
    stage_half(Wf, 0, 0, Wlds[0], wv, l);

    // ---- per-lane dist_vec for both owned edges (e0, e0+16) ----
    const float* cgb = cg_xyz + (size_t)b * NCGS * 3;
    const float cx = cgb[cg*3+0], cy = cgb[cg*3+1], cz = cgb[cg*3+2];
    const float d0x = cgb[(1+e0)*3+0]-cx,  d0y = cgb[(1+e0)*3+1]-cy,  d0z = cgb[(1+e0)*3+2]-cz;
    const float d1x = cgb[(17+e0)*3+0]-cx, d1y = cgb[(17+e0)*3+1]-cy, d1z = cgb[(17+e0)*3+2]-cz;
    const float dist0 = sqrtf(d0x*d0x + d0y*d0y + d0z*d0z);
    const float dist1 = sqrtf(d1x*d1x + d1y*d1y + d1z*d1z);

    // ---- RBF features directly into B-fragments (identity k-labeling) ----
    const float STEP  = 10.0f / 127.0f;
    const float COEFF = -0.5f / (STEP * STEP);
    bf16x8 bh[2][4], bl[2][4];
    #pragma unroll
    for (int rt = 0; rt < 2; ++rt) {
        float dd = rt ? dist1 : dist0;
        #pragma unroll
        for (int kc = 0; kc < 4; ++kc) {
            U16B H, L;
            #pragma unroll
            for (int w = 0; w < 4; ++w) {
                int k0 = kc*32 + g*8 + 2*w;
                float t0 = dd - (float)k0 * STEP;
                float t1 = dd - (float)(k0+1) * STEP;
                float e0f = __expf(COEFF * t0 * t0);
                float e1f = __expf(COEFF * t1 * t1);
                uint b0 = __float_as_uint(e0f), b1 = __float_as_uint(e1f);
                H.u[w] = (b0 >> 16) | (b1 & 0xffff0000u);
                float l0 = e0f - __uint_as_float(b0 & 0xffff0000u);
                float l1 = e1f - __uint_as_float(b1 & 0xffff0000u);
                L.u[w] = (__float_as_uint(l0) >> 16) | (__float_as_uint(l1) & 0xffff0000u);
            }
            bh[rt][kc] = H.v; bl[rt][kc] = L.v;
        }
    }

    asm volatile("s_waitcnt vmcnt(0)" ::: "memory");
    __syncthreads();                         // half 0 of step 0 ready

    // ---- 13 MFMA steps; per step: 2 halves, staged one ahead ----
    f32x4 acc[8][2];
    for (int s = 0; s < 13; ++s) {
        const float* bias; int md;
        {
            int d = s >> 2, ph = s & 3;
            if      (s == 12)  { bias = dec_b1;        md = 0; }
            else if (ph == 0)  { bias = mlp_b1 + d*KF; md = 0; }
            else if (ph == 1)  { bias = mlp_b2 + d*KF; md = 1; }
            else if (ph == 2)  { bias = upd_b1 + d*KF; md = 0; }
            else               { bias = upd_b2 + d*KF; md = 2; }
        }

        // stage half1 of this step into buf B
        stage_half(Wf, s, 1, Wlds[1], wv, l);

        // acc init folds the bias (C row = feature = ft*16 + 4g + q)
        #pragma unroll
        for (int ft = 0; ft < 8; ++ft) {
            float4 bv = *(const float4*)(bias + ft*16 + g*4);
            acc[ft][0] = (f32x4){bv.x, bv.y, bv.z, bv.w};
            acc[ft][1] = acc[ft][0];
        }

        // compute half0 (kc 0,1) from buf A
        comp_grp<0,0>(Wlds[0], l, bh, bl, acc);
        comp_grp<0,1>(Wlds[0], l, bh, bl, acc);
        comp_grp<1,0>(Wlds[0], l, bh, bl, acc);
        comp_grp<1,1>(Wlds[0], l, bh, bl, acc);

        asm volatile("s_waitcnt vmcnt(0)" ::: "memory");
        __syncthreads();                     // half1 ready; half0 reads done

        // stage half0 of next step into buf A
        if (s < 12) stage_half(Wf, s+1, 0, Wlds[0], wv, l);

        // compute half1 (kc 2,3) from buf B
        comp_grp<2,0>(Wlds[1], l, bh, bl, acc);
        comp_grp<2,1>(Wlds[1], l, bh, bl, acc);
        comp_grp<3,0>(Wlds[1], l, bh, bl, acc);
        comp_grp<3,1>(Wlds[1], l, bh, bl, acc);

        // epilogue: (relu | mean | plain) — bias already folded
        if (md == 0) {
            #pragma unroll
            for (int ft = 0; ft < 8; ++ft)
                #pragma unroll
                for (int rt = 0; rt < 2; ++rt)
                    #pragma unroll
                    for (int q = 0; q < 4; ++q)
                        acc[ft][rt][q] = fmaxf(acc[ft][rt][q], 0.f);
        } else if (md == 1) {
            #pragma unroll
            for (int ft = 0; ft < 8; ++ft)
                #pragma unroll
                for (int q = 0; q < 4; ++q) {
                    float sm = acc[ft][0][q] + acc[ft][1][q];
                    sm += __shfl_xor(sm, 1);
                    sm += __shfl_xor(sm, 2);
                    sm += __shfl_xor(sm, 4);
                    sm += __shfl_xor(sm, 8);
                    float mn = sm * (1.0f / 32.0f);
                    acc[ft][0][q] += mn;
                    acc[ft][1][q] += mn;
                }
        }

        // repack accumulators as next step's B-fragments (pure registers)
        if (s < 12) {
            #pragma unroll
            for (int rt = 0; rt < 2; ++rt)
                #pragma unroll
                for (int kc = 0; kc < 4; ++kc) {
                    float v0 = acc[kc  ][rt][0], v1 = acc[kc  ][rt][1];
                    float v2 = acc[kc  ][rt][2], v3 = acc[kc  ][rt][3];
                    float v4 = acc[kc+4][rt][0], v5 = acc[kc+4][rt][1];
                    float v6 = acc[kc+4][rt][2], v7 = acc[kc+4][rt][3];
                    uint u0=__float_as_uint(v0), u1=__float_as_uint(v1);
                    uint u2=__float_as_uint(v2), u3=__float_as_uint(v3);
                    uint u4=__float_as_uint(v4), u5=__float_as_uint(v5);
                    uint u6=__float_as_uint(v6), u7=__float_as_uint(v7);
                    U16B H, L;
                    H.u[0] = (u0>>16)|(u1&0xffff0000u);
                    H.u[1] = (u2>>16)|(u3&0xffff0000u);
                    H.u[2] = (u4>>16)|(u5&0xffff0000u);
                    H.u[3] = (u6>>16)|(u7&0xffff0000u);
                    float l0=v0-__uint_as_float(u0&0xffff0000u), l1=v1-__uint_as_float(u1&0xffff0000u);
                    float l2=v2-__uint_as_float(u2&0xffff0000u), l3=v3-__uint_as_float(u3&0xffff0000u);
                    float l4=v4-__uint_as_float(u4&0xffff0000u), l5=v5-__uint_as_float(u5&0xffff0000u);
                    float l6=v6-__uint_as_float(u6&0xffff0000u), l7=v7-__uint_as_float(u7&0xffff0000u);
                    L.u[0] = (__float_as_uint(l0)>>16)|(__float_as_uint(l1)&0xffff0000u);
                    L.u[1] = (__float_as_uint(l2)>>16)|(__float_as_uint(l3)&0xffff0000u);
                    L.u[2] = (__float_as_uint(l4)>>16)|(__float_as_uint(l5)&0xffff0000u);
                    L.u[3] = (__float_as_uint(l6)>>16)|(__float_as_uint(l7)&0xffff0000u);
                    bh[rt][kc] = H.v; bl[rt][kc] = L.v;
                }
        }

        asm volatile("s_waitcnt vmcnt(0)" ::: "memory");
        __syncthreads();                     // next half0 ready; half1 reads done
    }

    // ---- G partials: butterfly over the 16 edge-lanes, 8-sliced atomics ----
    const int slice = blockIdx.x & (NSLICE-1);
    float* Gb = Gp + ((size_t)slice*BATCH + b) * KF * 3;
    #pragma unroll
    for (int ft = 0; ft < 8; ++ft) {
        #pragma unroll
        for (int q = 0; q < 4; ++q) {
            float r0 = acc[ft][0][q], r1 = acc[ft][1][q];
            float px = r0*d0x + r1*d1x;
            float py = r0*d0y + r1*d1y;
            float pz = r0*d0z + r1*d1z;
            px += __shfl_xor(px, 1); py += __shfl_xor(py, 1); pz += __shfl_xor(pz, 1);
            px += __shfl_xor(px, 2); py += __shfl_xor(py, 2); pz += __shfl_xor(pz, 2);
            px += __shfl_xor(px, 4); py += __shfl_xor(py, 4); pz += __shfl_xor(pz, 4);
            px += __shfl_xor(px, 8); py += __shfl_xor(py, 8); pz += __shfl_xor(pz, 8);
            if (e0 < 3) {
                float pv = (e0 == 0) ? px : ((e0 == 1) ? py : pz);
                atomicAdd(Gb + (16*ft + 4*g + q)*3 + e0, pv);
            }
        }
    }
}

// ---------------------------------------------------------------------------
// dx_recon[b,o,n] = sum_k dec_W2[k,o]*G[b,k,n] + dec_b2[o]*S[b,n]
// ---------------------------------------------------------------------------
__global__ __launch_bounds__(256)
void dx_kernel(const float* __restrict__ cg_xyz, const float* __restrict__ dec_W2,
               const float* __restrict__ dec_b2, const float* __restrict__ Gp,
               float* __restrict__ dxr)
{
    __shared__ float Gl[KF * 3];
    __shared__ float red[256 * 3];
    const int tid = threadIdx.x;
    const int b   = blockIdx.x >> 2;
    const int og  = blockIdx.x & 3;

    if (tid < 192) {
        float s0 = 0.f, s1 = 0.f;
        #pragma unroll
        for (int sl = 0; sl < NSLICE; ++sl) {
            const float* gp = Gp + ((size_t)sl*BATCH + b) * KF * 3;
            s0 += gp[tid]; s1 += gp[tid + 192];
        }
        Gl[tid] = s0; Gl[tid + 192] = s1;
    }
    const float* cgb = cg_xyz + (size_t)b * NCGS * 3;
    float w = ((tid >= 1 && tid <= 32) ? 256.f : 0.f) - 32.f;
    red[tid]       = w * cgb[tid*3+0];
    red[256 + tid] = w * cgb[tid*3+1];
    red[512 + tid] = w * cgb[tid*3+2];
    __syncthreads();
    for (int s2 = 128; s2 > 0; s2 >>= 1) {
        if (tid < s2) {
            red[tid]       += red[tid + s2];
            red[256 + tid] += red[256 + tid + s2];
            red[512 + tid] += red[512 + tid + s2];
        }
        __syncthreads();
    }
    const float S0 = red[0], S1 = red[256], S2 = red[512];

    const int o = og * 256 + tid;
    const float bq = dec_b2[o];
    float a0 = bq * S0, a1 = bq * S1, a2 = bq * S2;
    #pragma unroll 4
    for (int k = 0; k < KF; ++k) {
        float wvv = dec_W2[k * NATOMS + o];
        a0 = fmaf(wvv, Gl[k*3+0], a0);
        a1 = fmaf(wvv, Gl[k*3+1], a1);
        a2 = fmaf(wvv, Gl[k*3+2], a2);
    }
    float* dp = dxr + ((size_t)b * NATOMS + o) * 3;
    dp[0] = a0; dp[1] = a1; dp[2] = a2;
}

// ---------------------------------------------------------------------------
__global__ __launch_bounds__(256)
void cgo_kernel(const float* __restrict__ assign_norm, const float* __restrict__ dxr,
                float* __restrict__ cgo)
{
    __shared__ float dxl[64 * 3];
    const int tid = threadIdx.x;
    const int b   = blockIdx.x >> 4;
    const int a0  = (blockIdx.x & 15) * 64;
    if (tid < 192) dxl[tid] = dxr[((size_t)b * NATOMS + a0) * 3 + tid];
    __syncthreads();
    float c0 = 0.f, c1 = 0.f, c2 = 0.f;
    const float* an = assign_norm + ((size_t)b * NATOMS + a0) * NCGS + tid;
    #pragma unroll 4
    for (int a = 0; a < 64; ++a) {
        float v = an[(size_t)a * NCGS];
        c0 = fmaf(v, dxl[a*3+0], c0);
        c1 = fmaf(v, dxl[a*3+1], c1);
        c2 = fmaf(v, dxl[a*3+2], c2);
    }
    float* cp = cgo + ((size_t)b * NCGS + tid) * 3;
    atomicAdd(cp+0, c0); atomicAdd(cp+1, c1); atomicAdd(cp+2, c2);
}

// ---------------------------------------------------------------------------
__global__ __launch_bounds__(256)
void recon_kernel(const float* __restrict__ cg_xyz, const float* __restrict__ cgo,
                  const float* __restrict__ dxr, const int* __restrict__ assign_idx,
                  float* __restrict__ out)
{
    int i = blockIdx.x * 256 + threadIdx.x;
    int b   = i / (NATOMS * 3);
    int rem = i - b * (NATOMS * 3);
    int a   = rem / 3;
    int n   = rem - a * 3;
    int ia  = assign_idx[a];
    float v = cg_xyz[((size_t)b*NCGS + ia)*3 + n]
            - cgo[((size_t)b*NCGS + ia)*3 + n]
            + dxr[((size_t)b*NATOMS + a)*3 + n];
    out[i] = v;
}

// ---------------------------------------------------------------------------
extern "C" void kernel_launch(void* const* d_in, const int* in_sizes, int n_in,
                              void* d_out, int out_size, void* d_ws, size_t ws_size,
                              hipStream_t stream)
{
    const float* soft_assign = (const float*)d_in[0];
    const float* xyz         = (const float*)d_in[1];
    const float* cg_xyz      = (const float*)d_in[2];
    const float* assign_norm = (const float*)d_in[3];
    const int*   assign_idx  = (const int*)  d_in[4];
    const float* mlp_W1 = (const float*)d_in[5];
    const float* mlp_b1 = (const float*)d_in[6];
    const float* mlp_W2 = (const float*)d_in[7];
    const float* mlp_b2 = (const float*)d_in[8];
    const float* upd_W1 = (const float*)d_in[9];
    const float* upd_b1 = (const float*)d_in[10];
    const float* upd_W2 = (const float*)d_in[11];
    const float* upd_b2 = (const float*)d_in[12];
    const float* dec_W1 = (const float*)d_in[13];
    const float* dec_b1 = (const float*)d_in[14];
    const float* dec_W2 = (const float*)d_in[15];
    const float* dec_b2 = (const float*)d_in[16];

    float* out = (float*)d_out;

    // ws layout: Wswz (832 KB) | Gp (192 KB) | cgo (48 KB) | dxr (192 KB)
    uint*  Wswz = (uint*)d_ws;
    float* Gp   = (float*)d_ws + NFRAG*2*64*4;
    float* cgo  = Gp + NSLICE * BATCH * KF * 3;
    float* dxr  = cgo + BATCH * NCGS * 3;

    hipMemcpyAsync(out, soft_assign, (size_t)BATCH*NATOMS*NCGS*sizeof(float),
                   hipMemcpyDeviceToDevice, stream);
    hipMemcpyAsync(out + (size_t)BATCH*NATOMS*NCGS, xyz,
                   (size_t)BATCH*NATOMS*3*sizeof(float),
                   hipMemcpyDeviceToDevice, stream);
    hipMemsetAsync(Gp, 0,
        (size_t)(NSLICE*BATCH*KF*3 + BATCH*NCGS*3)*sizeof(float), stream);

    prep_kernel<<<104, 256, 0, stream>>>(mlp_W1, mlp_W2, upd_W1, upd_W2, dec_W1, Wswz);
    mlp_kernel<<<BATCH*64, 256, 0, stream>>>(cg_xyz, (const char*)Wswz,
        mlp_b1, mlp_b2, upd_b1, upd_b2, dec_b1, Gp);
    dx_kernel<<<BATCH*4, 256, 0, stream>>>(cg_xyz, dec_W2, dec_b2, Gp, dxr);
    cgo_kernel<<<BATCH*16, 256, 0, stream>>>(assign_norm, dxr, cgo);
    recon_kernel<<<(BATCH*NATOMS*3)/256, 256, 0, stream>>>(
        cg_xyz, cgo, dxr, assign_idx,
        out + (size_t)BATCH*NATOMS*NCGS + (size_t)BATCH*NATOMS*3);
}